// Round 7
// baseline (285.632 us; speedup 1.0000x reference)
//
#include <hip/hip_runtime.h>
#include <cmath>

#define NN 8192
#define DD 512
#define NSRC 8
#define SPLITS 16
#define BM 128
#define BN 128
#define BK 64
#define CPS (NN / SPLITS)     // 512 cols per split
#define CTILES (CPS / BN)     // 4 column tiles per block
#define COFF 100.0f           // fixed softmax offset (R3-R6 validated: absmax 0)
#define SSBLK 128             // k_src_sums blocks (64 rows each)

typedef __bf16 bf16x8 __attribute__((ext_vector_type(8)));
typedef float  f32x16 __attribute__((ext_vector_type(16)));

__device__ __forceinline__ unsigned short f2bf(float f) {
    unsigned u = __float_as_uint(f);
    u += 0x7fffu + ((u >> 16) & 1u);
    return (unsigned short)(u >> 16);
}

// ---------------------------------------------------------------------------
// Kernel 0: fp32 -> bf16 cast (RNE). Block 0 zero-inits ps/Tsum/ctrs/out.
// ctrs layout: [0..7]=counts, [16]=ssdone, [32..95]=done[64]; zero 128 ints.
// ---------------------------------------------------------------------------
__global__ __launch_bounds__(256) void k_cast(
    const float* __restrict__ img, const float* __restrict__ txt,
    unsigned short* __restrict__ imgB, unsigned short* __restrict__ txtB,
    float* __restrict__ ps, float* __restrict__ Tsum,
    int* __restrict__ ctrs, float* __restrict__ out)
{
    if (blockIdx.x == 0) {
        const float4 z = {0.f, 0.f, 0.f, 0.f};
#pragma unroll
        for (int k = 0; k < 8; k++)     // ps: 8192 floats
            *(float4*)(ps + (k * 256 + threadIdx.x) * 4) = z;
#pragma unroll
        for (int k = 0; k < 4; k++)     // Tsum: 4096 floats
            *(float4*)(Tsum + (k * 256 + threadIdx.x) * 4) = z;
        if (threadIdx.x < 128) ctrs[threadIdx.x] = 0;
        if (threadIdx.x == 0) out[0] = 0.f;
    }
    const size_t gid = (size_t)blockIdx.x * 256 + threadIdx.x;
    const size_t half = (size_t)NN * DD / 8;   // chunks of 8 elements
    const float* src = (gid < half) ? img : txt;
    unsigned short* dst = (gid < half) ? imgB : txtB;
    const size_t off = ((gid < half) ? gid : gid - half) * 8;
    const float4 v0 = *(const float4*)(src + off);
    const float4 v1 = *(const float4*)(src + off + 4);
    union { unsigned short s[8]; uint4 v; } o;
    o.s[0] = f2bf(v0.x); o.s[1] = f2bf(v0.y); o.s[2] = f2bf(v0.z); o.s[3] = f2bf(v0.w);
    o.s[4] = f2bf(v1.x); o.s[5] = f2bf(v1.y); o.s[6] = f2bf(v1.z); o.s[7] = f2bf(v1.w);
    *(uint4*)(dst + off) = o.v;
}

// ---------------------------------------------------------------------------
// Kernel 1: per-source text sums + counts (R4-style register acc + atomic
// flush — measured equal to the store+reduce variant). Signals completion
// via ssdone so the fused finalize in k_lse_mfma can gate on Tsum/counts.
// ---------------------------------------------------------------------------
__global__ __launch_bounds__(256) void k_src_sums(
    const float* __restrict__ txt, const int* __restrict__ labels,
    float* __restrict__ Tsum, int* __restrict__ counts, int* __restrict__ ssdone)
{
    const int tid = threadIdx.x;
    const int d0 = 2 * tid;
    const int row0 = blockIdx.x * (NN / SSBLK);
    float accx[NSRC], accy[NSRC];
#pragma unroll
    for (int s = 0; s < NSRC; s++) { accx[s] = 0.f; accy[s] = 0.f; }

    __shared__ int cacc[NSRC];
    if (tid < NSRC) cacc[tid] = 0;
    __syncthreads();
    if (tid < (NN / SSBLK)) atomicAdd(&cacc[labels[row0 + tid]], 1);

#pragma unroll 4
    for (int j = 0; j < NN / SSBLK; j++) {
        const int lab = labels[row0 + j];
        const float2 v = *(const float2*)(txt + (size_t)(row0 + j) * DD + d0);
#pragma unroll
        for (int s = 0; s < NSRC; s++) {
            accx[s] += (lab == s) ? v.x : 0.f;
            accy[s] += (lab == s) ? v.y : 0.f;
        }
    }
#pragma unroll
    for (int s = 0; s < NSRC; s++) {
        atomicAdd(&Tsum[s * DD + d0],     accx[s]);
        atomicAdd(&Tsum[s * DD + d0 + 1], accy[s]);
    }
    __syncthreads();
    if (tid < NSRC) atomicAdd(&counts[tid], cacc[tid]);
    __syncthreads();                 // all block atomics drained (barrier waitcnt)
    if (tid == 0) {
        __threadfence();             // release Tsum/counts to agent scope
        atomicAdd(ssdone, 1);
    }
}

// ---------------------------------------------------------------------------
// Kernel 2: MFMA flash-lse (R5 body VERBATIM — 92 µs proven: 32x32x16, wave
// = 32 rows x 128 cols, 64 VGPR, 3 blocks/CU) + diag extraction + FUSED
// FINALIZE: the 16th split block of each row-group (done[by] counter) gates
// on ssdone, then computes its 128 rows' loss terms and atomicAdds to out.
// ---------------------------------------------------------------------------
__global__ __launch_bounds__(256, 4) void k_lse_mfma(
    const unsigned short* __restrict__ imgB, const unsigned short* __restrict__ txtB,
    const float* __restrict__ scale_p,
    float* __restrict__ ps, float* __restrict__ dsbuf,
    const float* __restrict__ img, const int* __restrict__ labels,
    const float* __restrict__ Tsum, int* __restrict__ counts,
    int* __restrict__ ssdone, int* __restrict__ done, float* __restrict__ out)
{
    __shared__ uint4 lds[2048];            // A: [0,1024), B: [1024,2048) chunks
    const float scale = scale_p[0];
    const int tid  = threadIdx.x;
    const int lane = tid & 63;
    const int w    = tid >> 6;             // wave id
    const int split = blockIdx.x & (SPLITS - 1);
    const int by    = blockIdx.x / SPLITS;
    const int row0  = by * BM;
    const int colBase = split * CPS;
    const int lo = lane & 31;              // row/col within 32-tile
    const int hi = lane >> 5;              // k-half selector
    const bool diagBlk = (split == (by >> 2));
    const int  diagCt  = by & 3;

    // staging geometry: thread stages physical chunk p = t*256 + tid
    int st_r[4], st_kc[4];
#pragma unroll
    for (int t = 0; t < 4; t++) {
        const int p = t * 256 + tid;
        st_r[t]  = p >> 3;
        st_kc[t] = (p & 7) ^ (st_r[t] & 7);
    }

    // fragment read bases (uint4 chunk indices)
    const int ar = w * 32 + lo;            // A row for this lane
    const int aIdx = ar * 8, aSw = ar & 7;
    int bIdx[4], bSw[4];
#pragma unroll
    for (int j = 0; j < 4; j++) {
        const int c = j * 32 + lo;         // B col for this lane
        bIdx[j] = 1024 + c * 8; bSw[j] = c & 7;
    }

    float s_run[16];
#pragma unroll
    for (int rg = 0; rg < 16; rg++) s_run[rg] = 0.f;

    for (int ct = 0; ct < CTILES; ct++) {
        const int col0 = colBase + ct * BN;
        f32x16 acc[4];
#pragma unroll
        for (int j = 0; j < 4; j++)
#pragma unroll
            for (int rg = 0; rg < 16; rg++) acc[j][rg] = 0.f;

        for (int kt = 0; kt < DD; kt += BK) {
            __syncthreads();               // previous tile's LDS reads done
#pragma unroll
            for (int t = 0; t < 4; t++) {  // stage A (128 rows x 64 k)
                const unsigned short* g =
                    imgB + (size_t)(row0 + st_r[t]) * DD + kt + (st_kc[t] << 3);
                __builtin_amdgcn_global_load_lds(
                    (const __attribute__((address_space(1))) void*)g,
                    (__attribute__((address_space(3))) void*)&lds[t * 256 + (w << 6)],
                    16, 0, 0);
            }
#pragma unroll
            for (int t = 0; t < 4; t++) {  // stage B (128 cols x 64 k)
                const unsigned short* g =
                    txtB + (size_t)(col0 + st_r[t]) * DD + kt + (st_kc[t] << 3);
                __builtin_amdgcn_global_load_lds(
                    (const __attribute__((address_space(1))) void*)g,
                    (__attribute__((address_space(3))) void*)&lds[1024 + t * 256 + (w << 6)],
                    16, 0, 0);
            }
            __syncthreads();               // drain global_load_lds
#pragma unroll
            for (int ks = 0; ks < 4; ks++) {   // 4 k-steps of 16
                const int kc = ks * 2 + hi;    // lane's k-chunk within BK
                const bf16x8 af = *reinterpret_cast<const bf16x8*>(
                    &lds[aIdx + (kc ^ aSw)]);
                bf16x8 bf[4];
#pragma unroll
                for (int j = 0; j < 4; j++)
                    bf[j] = *reinterpret_cast<const bf16x8*>(
                        &lds[bIdx[j] + (kc ^ bSw[j])]);
#pragma unroll
                for (int j = 0; j < 4; j++)
                    acc[j] = __builtin_amdgcn_mfma_f32_32x32x16_bf16(
                        af, bf[j], acc[j], 0, 0, 0);
            }
        }
        // diagonal extraction (raw dot, pre-scale) — R5-verified lane algebra
        if (diagBlk && ct == diagCt) {
            const int myrg = (lo & 3) + 4 * (lo >> 3);
            const bool mine = (hi == ((lo >> 2) & 1));
#pragma unroll
            for (int j = 0; j < 4; j++) if (j == w) {
                float dval = 0.f;
#pragma unroll
                for (int rg = 0; rg < 16; rg++)
                    dval = (rg == myrg) ? acc[j][rg] : dval;
                if (mine) dsbuf[row0 + w * 32 + lo] = dval;
            }
        }
        // epilogue: exp(logit - COFF), per-lane accumulation only
#pragma unroll
        for (int j = 0; j < 4; j++)
#pragma unroll
        for (int rg = 0; rg < 16; rg++)
            s_run[rg] += __expf(fmaf(acc[j][rg], scale, -COFF));
    }
    // reduce over the 32 col-lanes (xor offsets stay within the 32-group)
#pragma unroll
    for (int rg = 0; rg < 16; rg++) {
        float es = s_run[rg];
#pragma unroll
        for (int off = 16; off; off >>= 1) es += __shfl_xor(es, off);
        s_run[rg] = es;
    }
    if (lo == 0) {
#pragma unroll
        for (int rg = 0; rg < 16; rg++) {
            const int row = row0 + w * 32 + (rg & 3) + 8 * (rg >> 2) + 4 * hi;
            atomicAdd(&ps[row], s_run[rg]);
        }
    }

    // ---- fused finalize: last-of-16 split block for this row-group ----
    __syncthreads();                 // all waves' ps atomics / dsbuf stores drained
    __shared__ int amLast;
    if (tid == 0) {
        __threadfence();             // release ps/dsbuf to agent scope
        amLast = (atomicAdd(&done[by], 1) == SPLITS - 1);
    }
    __syncthreads();
    if (!amLast) return;

    if (tid == 0) {                  // gate on Tsum/counts readiness
        while (__hip_atomic_load(ssdone, __ATOMIC_ACQUIRE,
                                 __HIP_MEMORY_SCOPE_AGENT) < SSBLK)
            __builtin_amdgcn_s_sleep(8);
    }
    __syncthreads();
    __threadfence();

    float local = 0.f;
    for (int it = 0; it < 32; it++) {
        const int i = row0 + w * 32 + it;
        const int lab = labels[i];
        float dt = 0.f;
        const float* ip = img + (size_t)i * DD;
        const float* sp = Tsum + lab * DD;
#pragma unroll
        for (int k = lane; k < DD; k += 64)
            dt = fmaf(ip[k], sp[k], dt);
#pragma unroll
        for (int off = 32; off; off >>= 1) dt += __shfl_xor(dt, off);
        if (lane == 0) {
            const float pv = __hip_atomic_load(&ps[i], __ATOMIC_RELAXED,
                                               __HIP_MEMORY_SCOPE_AGENT);
            const float lse = COFF + __logf(pv);
            const int cnt = counts[lab] - 1;
            if (cnt > 0)
                local += (scale * (dt - dsbuf[i]) - (float)cnt * lse) / (float)cnt;
        }
    }
    __shared__ float red[4];
    if (lane == 0) red[w] = local;
    __syncthreads();
    if (tid == 0)
        atomicAdd(out, -(red[0] + red[1] + red[2] + red[3]) / (float)NN);
}

// ---------------------------------------------------------------------------
extern "C" void kernel_launch(void* const* d_in, const int* in_sizes, int n_in,
                              void* d_out, int out_size, void* d_ws, size_t ws_size,
                              hipStream_t stream)
{
    const float* img     = (const float*)d_in[0];
    const float* txt     = (const float*)d_in[1];
    const float* scale_p = (const float*)d_in[2];
    const int*   labels  = (const int*)d_in[3];
    float* out = (float*)d_out;

    char* ws = (char*)d_ws;
    float* ps     = (float*)(ws);                        // 32 KB
    float* dsbuf  = (float*)(ws + 32 * 1024);            // 32 KB
    float* Tsum   = (float*)(ws + 64 * 1024);            // 16 KB
    int*   ctrs   = (int*)(ws + 80 * 1024);              // 128 ints
    int*   counts = ctrs;                                // [0..7]
    int*   ssdone = ctrs + 16;                           // [16]
    int*   done   = ctrs + 32;                           // [32..95]
    unsigned short* imgB = (unsigned short*)(ws + 2 * 1024 * 1024);   // 8 MB
    unsigned short* txtB = (unsigned short*)(ws + 10 * 1024 * 1024);  // 8 MB

    k_cast<<<(2 * NN * DD / 8) / 256, 256, 0, stream>>>(img, txt, imgB, txtB,
                                                        ps, Tsum, ctrs, out);
    k_src_sums<<<SSBLK, 256, 0, stream>>>(txt, labels, Tsum, counts, ssdone);
    k_lse_mfma<<<(NN / BM) * SPLITS, 256, 0, stream>>>(imgB, txtB, scale_p,
                                                       ps, dsbuf, img, labels,
                                                       Tsum, counts, ssdone,
                                                       done, out);
}

// Round 8
// 189.673 us; speedup vs baseline: 1.5059x; 1.5059x over previous
//
#include <hip/hip_runtime.h>
#include <cmath>

#define NN 8192
#define DD 512
#define NSRC 8
#define SPLITS 16
#define BM 128
#define BN 128
#define BK 64
#define CPS (NN / SPLITS)     // 512 cols per split
#define CTILES (CPS / BN)     // 4 column tiles per block
#define COFF 100.0f           // fixed softmax offset (R3-R7 validated: absmax 0)
#define SSBLK 128             // src-partial blocks (64 rows each)
#define CASTB 4096            // cast blocks in merged pre-kernel

typedef __bf16 bf16x8 __attribute__((ext_vector_type(8)));
typedef float  f32x16 __attribute__((ext_vector_type(16)));

__device__ __forceinline__ unsigned short f2bf(float f) {
    unsigned u = __float_as_uint(f);
    u += 0x7fffu + ((u >> 16) & 1u);
    return (unsigned short)(u >> 16);
}

// ---------------------------------------------------------------------------
// Kernel A (merged): blocks [0,4096) = fp32->bf16 cast; blocks [4096,4224) =
// per-source text-sum partials (plain stores, NO atomics, NO init needed).
// ---------------------------------------------------------------------------
__global__ __launch_bounds__(256) void k_pre(
    const float* __restrict__ img, const float* __restrict__ txt,
    unsigned short* __restrict__ imgB, unsigned short* __restrict__ txtB,
    const int* __restrict__ labels,
    float* __restrict__ Tpart, int* __restrict__ cpart)
{
    const int tid = threadIdx.x;
    if (blockIdx.x < CASTB) {
        const size_t gid = (size_t)blockIdx.x * 256 + tid;
        const size_t half = (size_t)NN * DD / 8;   // chunks of 8 elements
        const float* src = (gid < half) ? img : txt;
        unsigned short* dst = (gid < half) ? imgB : txtB;
        const size_t off = ((gid < half) ? gid : gid - half) * 8;
        const float4 v0 = *(const float4*)(src + off);
        const float4 v1 = *(const float4*)(src + off + 4);
        union { unsigned short s[8]; uint4 v; } o;
        o.s[0] = f2bf(v0.x); o.s[1] = f2bf(v0.y); o.s[2] = f2bf(v0.z); o.s[3] = f2bf(v0.w);
        o.s[4] = f2bf(v1.x); o.s[5] = f2bf(v1.y); o.s[6] = f2bf(v1.z); o.s[7] = f2bf(v1.w);
        *(uint4*)(dst + off) = o.v;
        return;
    }
    // ---- src-partial part ----
    const int b = blockIdx.x - CASTB;
    const int d0 = 2 * tid;
    const int row0 = b * (NN / SSBLK);
    float accx[NSRC], accy[NSRC];
#pragma unroll
    for (int s = 0; s < NSRC; s++) { accx[s] = 0.f; accy[s] = 0.f; }

    __shared__ int cacc[NSRC];
    if (tid < NSRC) cacc[tid] = 0;
    __syncthreads();
    if (tid < (NN / SSBLK)) atomicAdd(&cacc[labels[row0 + tid]], 1);

#pragma unroll 4
    for (int j = 0; j < NN / SSBLK; j++) {
        const int lab = labels[row0 + j];
        const float2 v = *(const float2*)(txt + (size_t)(row0 + j) * DD + d0);
#pragma unroll
        for (int s = 0; s < NSRC; s++) {
            accx[s] += (lab == s) ? v.x : 0.f;
            accy[s] += (lab == s) ? v.y : 0.f;
        }
    }
    float* tp = Tpart + (size_t)b * (NSRC * DD);
#pragma unroll
    for (int s = 0; s < NSRC; s++) {
        float2 v; v.x = accx[s]; v.y = accy[s];
        *(float2*)(tp + s * DD + d0) = v;
    }
    __syncthreads();
    if (tid < NSRC) cpart[b * NSRC + tid] = cacc[tid];
}

// ---------------------------------------------------------------------------
// Kernel B: MFMA flash-lse — R5 body VERBATIM (92 µs proven: 32x32x16 bf16,
// wave = 32 rows x 128 cols, 64 VGPR, LDS exactly 32768, fixed-offset exp,
// XOR swizzle). Changes vs R5: ps is a plain per-split store (no atomics,
// no init); blocks 0-15 absorb Tpart->Tsum reduce, block 16 reduces cpart->
// counts, block 17 zeroes out — all outside the hot loop.
// ---------------------------------------------------------------------------
__global__ __launch_bounds__(256, 4) void k_lse_mfma(
    const unsigned short* __restrict__ imgB, const unsigned short* __restrict__ txtB,
    const float* __restrict__ scale_p,
    const float* __restrict__ Tpart, float* __restrict__ Tsum,
    const int* __restrict__ cpart, int* __restrict__ counts,
    float* __restrict__ ps, float* __restrict__ dsbuf, float* __restrict__ out)
{
    __shared__ uint4 lds[2048];            // A: [0,1024), B: [1024,2048) chunks
    const int tid  = threadIdx.x;

    if (blockIdx.x < 16) {                 // absorbed Tsum reduce
        const int e = blockIdx.x * 256 + tid;
        float sum = 0.f;
#pragma unroll 8
        for (int b = 0; b < SSBLK; b++)
            sum += Tpart[(size_t)b * (NSRC * DD) + e];
        Tsum[e] = sum;
    } else if (blockIdx.x == 16) {         // absorbed counts reduce
        if (tid < NSRC) {
            int c = 0;
            for (int b = 0; b < SSBLK; b++) c += cpart[b * NSRC + tid];
            counts[tid] = c;
        }
    } else if (blockIdx.x == 17) {
        if (tid == 0) out[0] = 0.f;
    }

    const float scale = scale_p[0];
    const int lane = tid & 63;
    const int w    = tid >> 6;             // wave id
    const int split = blockIdx.x & (SPLITS - 1);
    const int by    = blockIdx.x / SPLITS;
    const int row0  = by * BM;
    const int colBase = split * CPS;
    const int lo = lane & 31;              // row/col within 32-tile
    const int hi = lane >> 5;              // k-half selector
    const bool diagBlk = (split == (by >> 2));
    const int  diagCt  = by & 3;

    // staging geometry: thread stages physical chunk p = t*256 + tid
    int st_r[4], st_kc[4];
#pragma unroll
    for (int t = 0; t < 4; t++) {
        const int p = t * 256 + tid;
        st_r[t]  = p >> 3;
        st_kc[t] = (p & 7) ^ (st_r[t] & 7);
    }

    // fragment read bases (uint4 chunk indices)
    const int ar = w * 32 + lo;            // A row for this lane
    const int aIdx = ar * 8, aSw = ar & 7;
    int bIdx[4], bSw[4];
#pragma unroll
    for (int j = 0; j < 4; j++) {
        const int c = j * 32 + lo;         // B col for this lane
        bIdx[j] = 1024 + c * 8; bSw[j] = c & 7;
    }

    float s_run[16];
#pragma unroll
    for (int rg = 0; rg < 16; rg++) s_run[rg] = 0.f;

    for (int ct = 0; ct < CTILES; ct++) {
        const int col0 = colBase + ct * BN;
        f32x16 acc[4];
#pragma unroll
        for (int j = 0; j < 4; j++)
#pragma unroll
            for (int rg = 0; rg < 16; rg++) acc[j][rg] = 0.f;

        for (int kt = 0; kt < DD; kt += BK) {
            __syncthreads();               // previous tile's LDS reads done
#pragma unroll
            for (int t = 0; t < 4; t++) {  // stage A (128 rows x 64 k)
                const unsigned short* g =
                    imgB + (size_t)(row0 + st_r[t]) * DD + kt + (st_kc[t] << 3);
                __builtin_amdgcn_global_load_lds(
                    (const __attribute__((address_space(1))) void*)g,
                    (__attribute__((address_space(3))) void*)&lds[t * 256 + (w << 6)],
                    16, 0, 0);
            }
#pragma unroll
            for (int t = 0; t < 4; t++) {  // stage B (128 cols x 64 k)
                const unsigned short* g =
                    txtB + (size_t)(colBase + ct * BN + st_r[t]) * DD + kt + (st_kc[t] << 3);
                __builtin_amdgcn_global_load_lds(
                    (const __attribute__((address_space(1))) void*)g,
                    (__attribute__((address_space(3))) void*)&lds[1024 + t * 256 + (w << 6)],
                    16, 0, 0);
            }
            __syncthreads();               // drain global_load_lds
#pragma unroll
            for (int ks = 0; ks < 4; ks++) {   // 4 k-steps of 16
                const int kc = ks * 2 + hi;    // lane's k-chunk within BK
                const bf16x8 af = *reinterpret_cast<const bf16x8*>(
                    &lds[aIdx + (kc ^ aSw)]);
                bf16x8 bf[4];
#pragma unroll
                for (int j = 0; j < 4; j++)
                    bf[j] = *reinterpret_cast<const bf16x8*>(
                        &lds[bIdx[j] + (kc ^ bSw[j])]);
#pragma unroll
                for (int j = 0; j < 4; j++)
                    acc[j] = __builtin_amdgcn_mfma_f32_32x32x16_bf16(
                        af, bf[j], acc[j], 0, 0, 0);
            }
        }
        // diagonal extraction (raw dot, pre-scale) — R5-verified lane algebra
        if (diagBlk && ct == diagCt) {
            const int myrg = (lo & 3) + 4 * (lo >> 3);
            const bool mine = (hi == ((lo >> 2) & 1));
#pragma unroll
            for (int j = 0; j < 4; j++) if (j == w) {
                float dval = 0.f;
#pragma unroll
                for (int rg = 0; rg < 16; rg++)
                    dval = (rg == myrg) ? acc[j][rg] : dval;
                if (mine) dsbuf[row0 + w * 32 + lo] = dval;
            }
        }
        // epilogue: exp(logit - COFF), per-lane accumulation only
#pragma unroll
        for (int j = 0; j < 4; j++)
#pragma unroll
        for (int rg = 0; rg < 16; rg++)
            s_run[rg] += __expf(fmaf(acc[j][rg], scale, -COFF));
    }
    // reduce over the 32 col-lanes (xor offsets stay within the 32-group)
#pragma unroll
    for (int rg = 0; rg < 16; rg++) {
        float es = s_run[rg];
#pragma unroll
        for (int off = 16; off; off >>= 1) es += __shfl_xor(es, off);
        s_run[rg] = es;
    }
    if (lo == 0) {
#pragma unroll
        for (int rg = 0; rg < 16; rg++) {
            const int row = row0 + w * 32 + (rg & 3) + 8 * (rg >> 2) + 4 * hi;
            ps[(size_t)row * SPLITS + split] = s_run[rg];
        }
    }
}

// ---------------------------------------------------------------------------
// Kernel C: lse = COFF + log(sum of 16 split partials), ds from dsbuf,
// dt = img_i . T_{lab_i}, loss reduce. 512 blocks x 4 waves x 4 rows.
// ---------------------------------------------------------------------------
__global__ __launch_bounds__(256) void k_finalize(
    const float* __restrict__ img,
    const int* __restrict__ labels, const float* __restrict__ scale_p,
    const float* __restrict__ Tsum, const int* __restrict__ counts,
    const float* __restrict__ ps, const float* __restrict__ dsbuf,
    float* __restrict__ out)
{
    const float scale = scale_p[0];
    const int tid = threadIdx.x;
    const int lane = tid & 63;
    const int wave = tid >> 6;
    const int rowBase = blockIdx.x * 16 + wave * 4;
    float local = 0.f;
#pragma unroll
    for (int it = 0; it < 4; it++) {
        const int i = rowBase + it;
        const int lab = labels[i];
        float dt = 0.f;
        const float* ip = img + (size_t)i * DD;
        const float* sp = Tsum + lab * DD;
#pragma unroll
        for (int k = lane; k < DD; k += 64)
            dt = fmaf(ip[k], sp[k], dt);
#pragma unroll
        for (int off = 32; off; off >>= 1) dt += __shfl_xor(dt, off);
        if (lane == 0) {
            float ssum = 0.f;
#pragma unroll
            for (int s = 0; s < SPLITS; s++)
                ssum += ps[(size_t)i * SPLITS + s];
            const float lse = COFF + __logf(ssum);
            const int cnt = counts[lab] - 1;
            if (cnt > 0)
                local += (scale * (dt - dsbuf[i]) - (float)cnt * lse) / (float)cnt;
        }
    }
    __shared__ float red[4];
    if (lane == 0) red[wave] = local;
    __syncthreads();
    if (tid == 0)
        atomicAdd(out, -(red[0] + red[1] + red[2] + red[3]) / (float)NN);
}

// ---------------------------------------------------------------------------
extern "C" void kernel_launch(void* const* d_in, const int* in_sizes, int n_in,
                              void* d_out, int out_size, void* d_ws, size_t ws_size,
                              hipStream_t stream)
{
    const float* img     = (const float*)d_in[0];
    const float* txt     = (const float*)d_in[1];
    const float* scale_p = (const float*)d_in[2];
    const int*   labels  = (const int*)d_in[3];
    float* out = (float*)d_out;

    char* ws = (char*)d_ws;
    float* ps     = (float*)(ws);                        // 512 KB
    float* dsbuf  = (float*)(ws + 512 * 1024);           // 32 KB
    float* Tsum   = (float*)(ws + 544 * 1024);           // 16 KB
    int*   counts = (int*)(ws + 560 * 1024);             // 32 B
    int*   cpart  = (int*)(ws + 576 * 1024);             // 4 KB
    unsigned short* imgB = (unsigned short*)(ws + 2 * 1024 * 1024);   // 8 MB
    unsigned short* txtB = (unsigned short*)(ws + 10 * 1024 * 1024);  // 8 MB
    float* Tpart  = (float*)(ws + 18 * 1024 * 1024);     // 2 MB

    k_pre<<<CASTB + SSBLK, 256, 0, stream>>>(img, txt, imgB, txtB, labels,
                                             Tpart, cpart);
    k_lse_mfma<<<(NN / BM) * SPLITS, 256, 0, stream>>>(imgB, txtB, scale_p,
                                                       Tpart, Tsum, cpart,
                                                       counts, ps, dsbuf, out);
    k_finalize<<<NN / 16, 256, 0, stream>>>(img, labels, scale_p,
                                            Tsum, counts, ps, dsbuf, out);
}